// Round 9
// baseline (128.868 us; speedup 1.0000x reference)
//
#include <hip/hip_runtime.h>
#include <hip/hip_bf16.h>

// Problem: V=50000, D=300, B=8, Q=128, W=16, L=8192
//   q_e[bq]   = sum_w emb[queries[bq,w]] / count(queries[bq,w]!=0)
//   sim[bq,l] = dot(q_e[bq], emb[labels[l]]) / max(|q_e[bq]|*|emb[labels[l]]|, 1e-8)
//   mask[bq,l]= (count!=0) && (labels[l]!=0)
// dtypes: emb float32, indices int32 (harness-converted), out float32.
// Output: sim (8,128,1,8192) then mask (8,128,1,8192) = 16,777,216 floats.
//
// Ladder: R6 packed frag-major layout (contiguous 1KB/wave frag loads),
// R7 qe tile -> LDS via global_load_lds w=16. R9: 64l x 128q tiles ->
// 1024 blocks @ 80KB LDS = 2 resident/CU = TWO ROUNDS per CU, so round-2
// compute overlaps round-1's 64MB store drain (R7/R8 were single-round:
// all blocks drained stores in phase with nothing to overlap).
// Packed offset for (row r, dim d): g=r>>4, rr=r&15, kb=d>>5, quad=(d>>3)&3,
// e=d&7 ->  g*5120 + kb*512 + quad*128 + rr*8 + e.

#define DD   300
#define WQ   16
#define NQ   1024         // B*Q
#define NL   8192
#define EPSV 1e-8f
#define GSTRIDE 5120      // elems per 16-row packed group (16*320)

typedef __bf16 bf16_t;
typedef __attribute__((ext_vector_type(8))) __bf16 bf16x8;
typedef __attribute__((ext_vector_type(4))) float f32x4;

// ---------- P: fused q_e + l_e build -> packed layout + fp32 norms + flags ----------
__global__ __launch_bounds__(320) void build_ql(const float* __restrict__ emb,
                                                const int* __restrict__ queries,
                                                const int* __restrict__ labels,
                                                bf16_t* __restrict__ qep,
                                                bf16_t* __restrict__ lep,
                                                float* __restrict__ qn,
                                                float* __restrict__ lnrm,
                                                int* __restrict__ hasq,
                                                int* __restrict__ hasl) {
  const int blk = blockIdx.x;
  const int d = threadIdx.x;       // 0..319
  __shared__ float red[5];
  float v;

  const int kb = d >> 5, quad = (d >> 3) & 3, e = d & 7;
  const size_t poff = (size_t)kb * 512 + quad * 128 + e;   // + g*GSTRIDE + rr*8

  if (blk < NQ) {
    int n = 0;
    int idx[WQ];
#pragma unroll
    for (int w = 0; w < WQ; ++w) {
      idx[w] = queries[blk * WQ + w];
      n += (idx[w] != 0) ? 1 : 0;
    }
    float s = 0.f;
    if (d < DD) {
#pragma unroll
      for (int w = 0; w < WQ; ++w)
        s += emb[(size_t)idx[w] * DD + d];
    }
    const float qv = (d < DD) ? (s / (float)n) : 0.f;
    qep[(size_t)(blk >> 4) * GSTRIDE + (blk & 15) * 8 + poff] = (bf16_t)qv;
    v = qv;
    if (d == 0) hasq[blk] = (n != 0) ? 1 : 0;
  } else {
    const int l = blk - NQ;
    const int r = labels[l];
    float lv = 0.f;
    if (d < DD) lv = emb[(size_t)r * DD + d];
    lep[(size_t)(l >> 4) * GSTRIDE + (l & 15) * 8 + poff] = (bf16_t)lv;
    v = lv;
    if (d == 0) hasl[l] = (r != 0) ? 1 : 0;
  }

  v = v * v;
#pragma unroll
  for (int off = 32; off > 0; off >>= 1) v += __shfl_down(v, off);
  if ((threadIdx.x & 63) == 0) red[threadIdx.x >> 6] = v;
  __syncthreads();
  if (threadIdx.x == 0) {
    const float nrm = sqrtf(red[0] + red[1] + red[2] + red[3] + red[4]);
    if (blk < NQ) qn[blk] = nrm; else lnrm[blk - NQ] = nrm;
  }
}

// ---------- G: 64l x 128q block, 4 waves each 16l x 128q ----------
// qe tile (128q x 320 packed = 80KB) staged to LDS once (global_load_lds w=16),
// b-frags via conflict-free ds_read_b128; single dbuf'd global a-frag per wave.
// Transposed product: A=le (m=l), B=qe (n=q); C: m=quad*4+reg (4 consecutive l),
// n=lane&15 (q) -> float4 stores to out[q][l].
// 1024 blocks @ 80KB LDS = 2 resident/CU = 2 rounds (store/compute overlap).
__global__ __launch_bounds__(256) void gemm_cos(const bf16_t* __restrict__ qep,
                                                const bf16_t* __restrict__ lep,
                                                const float* __restrict__ qn,
                                                const float* __restrict__ lnrm,
                                                const int* __restrict__ hasq,
                                                const int* __restrict__ hasl,
                                                float* __restrict__ out) {
  const int l0 = blockIdx.x * 64;   // label tile (MFMA m)
  const int q0 = blockIdx.y * 128;  // query tile (MFMA n)
  const int wave = threadIdx.x >> 6;
  const int lane = threadIdx.x & 63;
  const int l16 = lane & 15;
  const int quad = lane >> 4;

  __shared__ __align__(16) bf16_t qls[8 * GSTRIDE];   // 40960 elems = 80 KB

  // ---- stage packed qe tile (8 consecutive groups, fully contiguous) ----
  {
    const char* gsrc = (const char*)(qep + (size_t)(q0 >> 4) * GSTRIDE);
    char* lbase = (char*)qls;
#pragma unroll
    for (int t = 0; t < 20; ++t) {
      const int boff = (t * 256 + threadIdx.x) * 16;
      __builtin_amdgcn_global_load_lds(
          (const __attribute__((address_space(1))) void*)(gsrc + boff),
          (__attribute__((address_space(3))) void*)(lbase + boff),
          16, 0, 0);
    }
  }

  // a-frag base (this wave's single 16-row l-group)
  const bf16_t* ap = lep + (size_t)((l0 >> 4) + wave) * GSTRIDE + lane * 8;

  // epilogue scalars hoisted (independent of K-loop)
  const int lb = l0 + wave * 16 + quad * 4;   // 4 consecutive l per lane
  float lv[4];
  int hl[4];
#pragma unroll
  for (int r = 0; r < 4; ++r) {
    lv[r] = lnrm[lb + r];
    hl[r] = hasl[lb + r];
  }

  f32x4 acc[8] = {};   // [j over q-frags]
  bf16x8 a[2];

  __syncthreads();     // LDS tile ready (barrier drains global_load_lds)

  a[0] = *(const bf16x8*)(ap);

#pragma unroll
  for (int kb = 0; kb < 10; ++kb) {
    const int cur = kb & 1, nxt = cur ^ 1;
    if (kb < 9) a[nxt] = *(const bf16x8*)(ap + (kb + 1) * 512);
    bf16x8 b[8];
#pragma unroll
    for (int j = 0; j < 8; ++j)
      b[j] = *(const bf16x8*)(qls + (size_t)j * GSTRIDE + kb * 512 + lane * 8);
#pragma unroll
    for (int j = 0; j < 8; ++j)
      acc[j] = __builtin_amdgcn_mfma_f32_16x16x32_bf16(a[cur], b[j], acc[j], 0, 0, 0);
  }

  // ---- epilogue: lane covers l = lb..lb+3, q = q0 + j*16 + l16 ----
  float* const outm = out + (size_t)NQ * NL;
#pragma unroll
  for (int j = 0; j < 8; ++j) {
    const int q = q0 + j * 16 + l16;
    const float qv = qn[q];
    const int hq = hasq[q];
    const size_t rowb = (size_t)q * NL;
    f32x4 s, m;
#pragma unroll
    for (int r = 0; r < 4; ++r) {
      const float den = fmaxf(qv * lv[r], EPSV);
      s[r] = acc[j][r] * __builtin_amdgcn_rcpf(den);
      m[r] = (hq && hl[r]) ? 1.f : 0.f;
    }
    *(f32x4*)(out + rowb + lb) = s;
    *(f32x4*)(outm + rowb + lb) = m;
  }
}

extern "C" void kernel_launch(void* const* d_in, const int* in_sizes, int n_in,
                              void* d_out, int out_size, void* d_ws, size_t ws_size,
                              hipStream_t stream) {
  const float* emb = (const float*)d_in[0];     // 50000 x 300 f32
  const int* queries = (const int*)d_in[1];     // 8*128*16 int32
  const int* labels = (const int*)d_in[2];      // 8192 int32

  char* ws = (char*)d_ws;
  bf16_t* qep  = (bf16_t*)(ws);                 // 1024*320*2  = 655360 B (packed)
  bf16_t* lep  = (bf16_t*)(ws + 655360);        // 8192*320*2  = 5242880 B (packed)
  float*  qn   = (float*) (ws + 5898240);       // 1024*4
  float*  lnrm = (float*) (ws + 5902336);       // 8192*4
  int*    hasq = (int*)   (ws + 5935104);       // 1024*4
  int*    hasl = (int*)   (ws + 5939200);       // 8192*4  (end ~5.95 MB)

  float* out = (float*)d_out;

  build_ql<<<NQ + NL, 320, 0, stream>>>(emb, queries, labels, qep, lep, qn, lnrm, hasq, hasl);
  gemm_cos<<<dim3(NL / 64, NQ / 128), 256, 0, stream>>>(qep, lep, qn, lnrm, hasq, hasl, out);
}

// Round 10
// 125.889 us; speedup vs baseline: 1.0237x; 1.0237x over previous
//
#include <hip/hip_runtime.h>
#include <hip/hip_bf16.h>

// Problem: V=50000, D=300, B=8, Q=128, W=16, L=8192
//   q_e[bq]   = sum_w emb[queries[bq,w]] / count(queries[bq,w]!=0)
//   sim[bq,l] = dot(q_e[bq], emb[labels[l]]) / max(|q_e[bq]|*|emb[labels[l]]|, 1e-8)
//   mask[bq,l]= (count!=0) && (labels[l]!=0)
// dtypes: emb float32, indices int32 (harness-converted), out float32.
// Output: sim (8,128,1,8192) then mask (8,128,1,8192) = 16,777,216 floats.
//
// FINAL (= R7, measured best 125.8us): packed MFMA-fragment-major scratch
// layout (every frag load = contiguous 1KB/wave), qe tile staged to LDS via
// global_load_lds w=16, b-frags via conflict-free ds_read_b128, a-frags
// double-buffered global, transposed product for float4-coalesced epilogue.
// R8 (bigger tiles, half read traffic) and R9 (two-round store/compute
// overlap) were both neutral -> gemm is at its HBM-write-drain floor; the
// remaining window is fixed harness poison/restore traffic (~72us).
// Packed offset for (row r, dim d): g=r>>4, rr=r&15, kb=d>>5, quad=(d>>3)&3,
// e=d&7 ->  g*5120 + kb*512 + quad*128 + rr*8 + e.

#define DD   300
#define WQ   16
#define NQ   1024         // B*Q
#define NL   8192
#define EPSV 1e-8f
#define GSTRIDE 5120      // elems per 16-row packed group (16*320)

typedef __bf16 bf16_t;
typedef __attribute__((ext_vector_type(8))) __bf16 bf16x8;
typedef __attribute__((ext_vector_type(4))) float f32x4;

// ---------- P: fused q_e + l_e build -> packed layout + fp32 norms + flags ----------
__global__ __launch_bounds__(320) void build_ql(const float* __restrict__ emb,
                                                const int* __restrict__ queries,
                                                const int* __restrict__ labels,
                                                bf16_t* __restrict__ qep,
                                                bf16_t* __restrict__ lep,
                                                float* __restrict__ qn,
                                                float* __restrict__ lnrm,
                                                int* __restrict__ hasq,
                                                int* __restrict__ hasl) {
  const int blk = blockIdx.x;
  const int d = threadIdx.x;       // 0..319
  __shared__ float red[5];
  float v;

  const int kb = d >> 5, quad = (d >> 3) & 3, e = d & 7;
  const size_t poff = (size_t)kb * 512 + quad * 128 + e;   // + g*GSTRIDE + rr*8

  if (blk < NQ) {
    int n = 0;
    int idx[WQ];
#pragma unroll
    for (int w = 0; w < WQ; ++w) {
      idx[w] = queries[blk * WQ + w];
      n += (idx[w] != 0) ? 1 : 0;
    }
    float s = 0.f;
    if (d < DD) {
#pragma unroll
      for (int w = 0; w < WQ; ++w)
        s += emb[(size_t)idx[w] * DD + d];
    }
    const float qv = (d < DD) ? (s / (float)n) : 0.f;
    qep[(size_t)(blk >> 4) * GSTRIDE + (blk & 15) * 8 + poff] = (bf16_t)qv;
    v = qv;
    if (d == 0) hasq[blk] = (n != 0) ? 1 : 0;
  } else {
    const int l = blk - NQ;
    const int r = labels[l];
    float lv = 0.f;
    if (d < DD) lv = emb[(size_t)r * DD + d];
    lep[(size_t)(l >> 4) * GSTRIDE + (l & 15) * 8 + poff] = (bf16_t)lv;
    v = lv;
    if (d == 0) hasl[l] = (r != 0) ? 1 : 0;
  }

  v = v * v;
#pragma unroll
  for (int off = 32; off > 0; off >>= 1) v += __shfl_down(v, off);
  if ((threadIdx.x & 63) == 0) red[threadIdx.x >> 6] = v;
  __syncthreads();
  if (threadIdx.x == 0) {
    const float nrm = sqrtf(red[0] + red[1] + red[2] + red[3] + red[4]);
    if (blk < NQ) qn[blk] = nrm; else lnrm[blk - NQ] = nrm;
  }
}

// ---------- G: 128l x 64q block, 4 waves each 32l x 64q ----------
// qe tile (64q x 320 packed = 40KB) staged to LDS once (global_load_lds w=16),
// b-frags via ds_read_b128; a-frags direct packed global, double-buffered.
// Transposed product: A=le (m=l), B=qe (n=q); C: m=quad*4+reg (4 consecutive l),
// n=lane&15 (q) -> float4 stores to out[q][l]. 1024 blocks = 4/CU (LDS-capped).
__global__ __launch_bounds__(256) void gemm_cos(const bf16_t* __restrict__ qep,
                                                const bf16_t* __restrict__ lep,
                                                const float* __restrict__ qn,
                                                const float* __restrict__ lnrm,
                                                const int* __restrict__ hasq,
                                                const int* __restrict__ hasl,
                                                float* __restrict__ out) {
  const int l0 = blockIdx.x * 128;  // label tile (MFMA m)
  const int q0 = blockIdx.y * 64;   // query tile (MFMA n)
  const int wave = threadIdx.x >> 6;
  const int lane = threadIdx.x & 63;
  const int l16 = lane & 15;
  const int quad = lane >> 4;
  const int wl = wave * 32;         // this wave's l-offset within the block

  __shared__ __align__(16) bf16_t qls[4 * GSTRIDE];   // 20480 elems = 40 KB

  // ---- stage packed qe tile (4 consecutive groups, fully contiguous) ----
  {
    const char* gsrc = (const char*)(qep + (size_t)(q0 >> 4) * GSTRIDE);
    char* lbase = (char*)qls;
#pragma unroll
    for (int t = 0; t < 10; ++t) {
      const int boff = (t * 256 + threadIdx.x) * 16;
      __builtin_amdgcn_global_load_lds(
          (const __attribute__((address_space(1))) void*)(gsrc + boff),
          (__attribute__((address_space(3))) void*)(lbase + boff),
          16, 0, 0);
    }
  }

  // a-frag base (this wave's two 16-row l-groups)
  const bf16_t* ap = lep + (size_t)((l0 >> 4) + wave * 2) * GSTRIDE + lane * 8;

  f32x4 acc[2][4] = {};   // [i over l-frags][j over q-frags]
  bf16x8 a[2][2];

  __syncthreads();        // LDS tile ready (barrier drains global_load_lds)

#pragma unroll
  for (int i = 0; i < 2; ++i) a[0][i] = *(const bf16x8*)(ap + i * GSTRIDE);

#pragma unroll
  for (int kb = 0; kb < 10; ++kb) {
    const int cur = kb & 1, nxt = cur ^ 1;
    if (kb < 9) {
#pragma unroll
      for (int i = 0; i < 2; ++i)
        a[nxt][i] = *(const bf16x8*)(ap + i * GSTRIDE + (kb + 1) * 512);
    }
    bf16x8 b[4];
#pragma unroll
    for (int j = 0; j < 4; ++j)
      b[j] = *(const bf16x8*)(qls + (size_t)j * GSTRIDE + kb * 512 + lane * 8);
#pragma unroll
    for (int i = 0; i < 2; ++i)
#pragma unroll
      for (int j = 0; j < 4; ++j)
        acc[i][j] = __builtin_amdgcn_mfma_f32_16x16x32_bf16(a[cur][i], b[j],
                                                            acc[i][j], 0, 0, 0);
  }

  // ---- epilogue: lane covers l = lb..lb+3 (consecutive), q = q0 + j*16 + l16 ----
  float lv[2][4];
  int hl[2][4];
#pragma unroll
  for (int i = 0; i < 2; ++i) {
    const int lb = l0 + wl + i * 16 + quad * 4;
#pragma unroll
    for (int r = 0; r < 4; ++r) {
      lv[i][r] = lnrm[lb + r];
      hl[i][r] = hasl[lb + r];
    }
  }

  float* const outm = out + (size_t)NQ * NL;
#pragma unroll
  for (int j = 0; j < 4; ++j) {
    const int q = q0 + j * 16 + l16;
    const float qv = qn[q];
    const int hq = hasq[q];
    const size_t rowb = (size_t)q * NL;
#pragma unroll
    for (int i = 0; i < 2; ++i) {
      const int lb = l0 + wl + i * 16 + quad * 4;
      f32x4 s, m;
#pragma unroll
      for (int r = 0; r < 4; ++r) {
        const float den = fmaxf(qv * lv[i][r], EPSV);
        s[r] = acc[i][j][r] * __builtin_amdgcn_rcpf(den);
        m[r] = (hq && hl[i][r]) ? 1.f : 0.f;
      }
      *(f32x4*)(out + rowb + lb) = s;
      *(f32x4*)(outm + rowb + lb) = m;
    }
  }
}

extern "C" void kernel_launch(void* const* d_in, const int* in_sizes, int n_in,
                              void* d_out, int out_size, void* d_ws, size_t ws_size,
                              hipStream_t stream) {
  const float* emb = (const float*)d_in[0];     // 50000 x 300 f32
  const int* queries = (const int*)d_in[1];     // 8*128*16 int32
  const int* labels = (const int*)d_in[2];      // 8192 int32

  char* ws = (char*)d_ws;
  bf16_t* qep  = (bf16_t*)(ws);                 // 1024*320*2  = 655360 B (packed)
  bf16_t* lep  = (bf16_t*)(ws + 655360);        // 8192*320*2  = 5242880 B (packed)
  float*  qn   = (float*) (ws + 5898240);       // 1024*4
  float*  lnrm = (float*) (ws + 5902336);       // 8192*4
  int*    hasq = (int*)   (ws + 5935104);       // 1024*4
  int*    hasl = (int*)   (ws + 5939200);       // 8192*4  (end ~5.95 MB)

  float* out = (float*)d_out;

  build_ql<<<NQ + NL, 320, 0, stream>>>(emb, queries, labels, qep, lep, qn, lnrm, hasq, hasl);
  gemm_cos<<<dim3(NL / 128, NQ / 64), 256, 0, stream>>>(qep, lep, qn, lnrm, hasq, hasl, out);
}